// Round 1
// 217.651 us; speedup vs baseline: 1.0040x; 1.0040x over previous
//
#include <hip/hip_runtime.h>
#include <hip/hip_bf16.h>
#include <math.h>

#define B_  256
#define T_  512
#define D_  256
#define A_  50
#define EPS 1e-7f
#define NW  8    // waves per block (R10: was 16)

typedef short  short8  __attribute__((ext_vector_type(8)));
typedef float  floatx4 __attribute__((ext_vector_type(4)));

__device__ inline unsigned short f2bf(float f) {
    unsigned int u = __float_as_uint(f);
    u = (u + 0x7fffu + ((u >> 16) & 1u)) >> 16;   // RNE (inputs are finite)
    return (unsigned short)u;
}

// ---------------------------------------------------------------------------
// Prep: swizzle W [256][50] fp32 into bf16 B-fragment order for
// mfma_f32_16x16x32_bf16, zero-padded to N=64. Fragment (nt,ks), lane l,
// element j holds B[k][n] with n = nt*16 + (l&15), k = ks*32 + (l>>4)*8 + j.
// Layout: Wf[((nt*8+ks)*64 + l)*8 + j]. Also bias/u zero-padded to 64.
// (unchanged from R9)
// ---------------------------------------------------------------------------
__global__ void prep_kernel(const float* __restrict__ W,
                            const float* __restrict__ bias,
                            const float* __restrict__ u,
                            unsigned short* __restrict__ Wf,
                            float* __restrict__ bu64)
{
    int idx = blockIdx.x * 256 + threadIdx.x;      // 0 .. 16383
    int j  = idx & 7;
    int l  = (idx >> 3) & 63;
    int ks = (idx >> 9) & 7;
    int nt = idx >> 12;
    int n  = nt * 16 + (l & 15);
    int k  = ks * 32 + (l >> 4) * 8 + j;
    float val = (n < A_) ? W[k * A_ + n] : 0.0f;
    Wf[idx] = f2bf(val);
    if (idx < 64) {
        bu64[idx]      = (idx < A_) ? bias[idx] : 0.0f;
        bu64[64 + idx] = (idx < A_) ? u[idx]    : 0.0f;
    }
}

// pack 4 floats -> 4 bf16 (hardware v_cvt_pk_bf16_f32, RNE)
__device__ inline void pack_bf4(short8& av, int base, float fx, float fy,
                                float fz, float fw)
{
    union { __hip_bfloat162 h2; int i; } c0, c1;
    c0.h2 = __float22bfloat162_rn(make_float2(fx, fy));
    c1.h2 = __float22bfloat162_rn(make_float2(fz, fw));
    av[base + 0] = (short)(c0.i & 0xffff);
    av[base + 1] = (short)((unsigned)c0.i >> 16);
    av[base + 2] = (short)(c1.i & 0xffff);
    av[base + 3] = (short)((unsigned)c1.i >> 16);
}

// ---------------------------------------------------------------------------
// R10: SINGLE-PASS fusion. One block per batch (256 blocks x 512 threads,
// 8 waves, waves_per_eu(2,2) -> 256-VGPR budget, 1 block/CU).
//
// Key change vs R9 (two-phase): the softmax here has no max-subtract, so the
// denominator is a deferred scalar. Each wave computes the full scores for
// its own 16-row tile (K-reduction is inside the MFMA) while the lane's
// pre[] registers still hold that tile's x in f32 -> pool IMMEDIATELY into a
// per-lane register accumulator (acc2[16] float4 = the lane's 64 columns).
// This deletes phase 2 (134 MB L3 re-read) and the 9-barrier tree sum.
//
// MLP fix: per-wave register double-buffer pre[2][16] — tile t+1's 16 HBM
// loads are issued BEFORE tile t's MFMA/tanh/pool compute, so each wave keeps
// 16 KB in flight through its ~1500-cycle compute window (R9 had zero loads
// outstanding during compute -> 1.5 TB/s plateau).
//
// End: 4-step shfl_xor butterfly over the 16 c-lanes reduces acc2, c==0
// lanes write 1 KB/wave partials to LDS, wave 0 sums the 512 exp-scores,
// final 256 threads scale by 1/(sum+EPS) and store.
// ---------------------------------------------------------------------------
__global__ __launch_bounds__(512)
__attribute__((amdgpu_waves_per_eu(2, 2)))
void fused_kernel(const float* __restrict__ x,
                  const unsigned short* __restrict__ Wf,
                  const float* __restrict__ bu64,
                  float* __restrict__ out)
{
    __shared__ int4  Wl[2048];        // 32 KB: Wf staged, fragment order
    __shared__ float s_lds[T_];       // 2 KB: exp-scores
    __shared__ float part[NW * 256];  // 8 KB: per-wave pooled partials
    __shared__ float s_inv;

    const int tid  = threadIdx.x;
    const int w    = tid >> 6;
    const int l    = tid & 63;
    const int c    = l & 15;        // A-col / time-row-owner within tile
    const int quad = l >> 4;        // k-slice / C-row-group
    const int bb   = blockIdx.x;

    // Stage Wf -> LDS (32 KB, coalesced int4; 4 per thread at 512 threads)
    {
        const int4* __restrict__ wsrc = (const int4*)Wf;
        #pragma unroll
        for (int i = 0; i < 4; i++)
            Wl[tid + i * 512] = wsrc[tid + i * 512];
    }

    const float*  __restrict__ xb  = x + (size_t)bb * T_ * D_;
    const short8* __restrict__ wl8 = (const short8*)Wl;

    float bnc[4], unc[4];
    #pragma unroll
    for (int nt = 0; nt < 4; nt++) {
        bnc[nt] = bu64[nt * 16 + c];
        unc[nt] = bu64[64 + nt * 16 + c];
    }
    __syncthreads();   // Wl ready

    // ---- Single pass: 4 tiles of 16 rows per wave, rows [w*64, w*64+64) ----
    float4 pre[2][16];
    float4 acc2[16];
    #pragma unroll
    for (int i = 0; i < 16; i++)
        acc2[i] = make_float4(0.f, 0.f, 0.f, 0.f);

    // prologue: load tile 0
    {
        const float4* __restrict__ xr =
            (const float4*)(xb + (size_t)(w * 64 + c) * D_);
        #pragma unroll
        for (int i = 0; i < 16; i++)
            pre[0][i] = xr[(i >> 1) * 8 + quad * 2 + (i & 1)];
    }

    #pragma unroll
    for (int t = 0; t < 4; t++) {
        const int cur = t & 1;
        const int nxt = cur ^ 1;

        // prefetch tile t+1 (in flight across this tile's whole compute)
        if (t < 3) {
            const float4* __restrict__ xr =
                (const float4*)(xb + (size_t)(w * 64 + (t + 1) * 16 + c) * D_);
            #pragma unroll
            for (int i = 0; i < 16; i++)
                pre[nxt][i] = xr[(i >> 1) * 8 + quad * 2 + (i & 1)];
        }

        const int rowbase = w * 64 + t * 16;

        floatx4 acc[4];
        #pragma unroll
        for (int nt = 0; nt < 4; nt++) acc[nt] = (floatx4){0.f, 0.f, 0.f, 0.f};

        #pragma unroll
        for (int ks = 0; ks < 8; ks++) {
            const float4 a0 = pre[cur][2 * ks];
            const float4 a1 = pre[cur][2 * ks + 1];
            short8 av;
            pack_bf4(av, 0, a0.x, a0.y, a0.z, a0.w);
            pack_bf4(av, 4, a1.x, a1.y, a1.z, a1.w);
            #pragma unroll
            for (int nt = 0; nt < 4; nt++) {
                const short8 bv = wl8[(nt * 8 + ks) * 64 + l];  // ds_read_b128
                acc[nt] = __builtin_amdgcn_mfma_f32_16x16x32_bf16(av, bv, acc[nt], 0, 0, 0);
            }
        }

        // scores for this wave's 16 rows (C layout: col=c, row=quad*4+r)
        #pragma unroll
        for (int r = 0; r < 4; r++) {
            float v = 0.0f;
            #pragma unroll
            for (int nt = 0; nt < 4; nt++)
                v += tanhf(acc[nt][r] + bnc[nt]) * unc[nt];
            #pragma unroll
            for (int off = 1; off < 16; off <<= 1)
                v += __shfl_xor(v, off, 16);
            if (c == 0)
                s_lds[rowbase + quad * 4 + r] = expf(v);
        }

        // pooled accumulation from registers: weight = exp-score of THIS
        // lane's row (same-wave LDS RAW — in-order DS, no barrier needed)
        const float ec = s_lds[rowbase + c];
        #pragma unroll
        for (int i = 0; i < 16; i++) {
            acc2[i].x += pre[cur][i].x * ec;
            acc2[i].y += pre[cur][i].y * ec;
            acc2[i].z += pre[cur][i].z * ec;
            acc2[i].w += pre[cur][i].w * ec;
        }
    }

    // ---- reduce acc2 over the 16 c-lanes (butterfly, stays in quad group) ----
    #pragma unroll
    for (int off = 1; off < 16; off <<= 1) {
        #pragma unroll
        for (int i = 0; i < 16; i++) {
            acc2[i].x += __shfl_xor(acc2[i].x, off);
            acc2[i].y += __shfl_xor(acc2[i].y, off);
            acc2[i].z += __shfl_xor(acc2[i].z, off);
            acc2[i].w += __shfl_xor(acc2[i].w, off);
        }
    }

    // c==0 lanes (4 per wave) hold the wave's pooled partial; granule
    // g = (i>>1)*8 + quad*2 + (i&1) covers 0..63 exactly once.
    if (c == 0) {
        #pragma unroll
        for (int i = 0; i < 16; i++) {
            const int g = (i >> 1) * 8 + quad * 2 + (i & 1);
            *(float4*)&part[w * 256 + g * 4] = acc2[i];
        }
    }
    __syncthreads();   // all partials + all s_lds scores visible

    // ---- denominator: wave 0 sums the 512 exp-scores ----
    if (tid < 64) {
        float s = 0.0f;
        #pragma unroll
        for (int k = 0; k < 8; k++) s += s_lds[tid + k * 64];
        #pragma unroll
        for (int off = 1; off < 64; off <<= 1) s += __shfl_xor(s, off);
        if (tid == 0) s_inv = 1.0f / (s + EPS);
    }
    __syncthreads();

    // ---- final: sum the 8 wave partials, scale, store ----
    if (tid < 256) {
        float o = 0.0f;
        #pragma unroll
        for (int wv = 0; wv < NW; wv++) o += part[wv * 256 + tid];
        out[(size_t)bb * 256 + tid] = o * s_inv;
    }
}

// ---------------------------------------------------------------------------
extern "C" void kernel_launch(void* const* d_in, const int* in_sizes, int n_in,
                              void* d_out, int out_size, void* d_ws, size_t ws_size,
                              hipStream_t stream)
{
    const float* x = (const float*)d_in[0];
    const float* W = (const float*)d_in[1];
    const float* b = (const float*)d_in[2];
    const float* u = (const float*)d_in[3];

    unsigned short* Wf  = (unsigned short*)d_ws;          // 16384 u16
    float*         bu64 = (float*)(Wf + 16384);           // 128 f
    float*         out  = (float*)d_out;

    prep_kernel  <<<64,  256, 0, stream>>>(W, b, u, Wf, bu64);
    fused_kernel <<<B_,  512, 0, stream>>>(x, Wf, bu64, out);
}